// Round 5
// baseline (743.332 us; speedup 1.0000x reference)
//
#include <hip/hip_runtime.h>

// EHD layer: 3x3 x 8-orientation conv -> argmax+threshold -> 9-bin one-hot
// -> 5x5 box count / 25.
// R4: wave-autonomous. No LDS, no __syncthreads (no vmcnt(0) barrier drains).
// Each wave owns (batch, 16-row stripe, 60-col chunk); horizontal 5-sum via
// __shfl of bin indices; vertical 5-sum via rolling 5-register window.

#define NOR 8
#define HH  1024
#define WW  1024
#define H2  1018
#define W2  1018
#define RPW 16            // output rows per wave
#define CW  60            // valid output cols per wave (lanes 60-63 = halo)
#define NCH 17            // col chunks: 17*60 = 1020 >= 1018
#define PL  (H2 * W2)     // output plane elements

__global__ __launch_bounds__(256, 4)
void ehd_wave(const float* __restrict__ x,
              const float* __restrict__ masks,
              float* __restrict__ out)
{
    const int lane  = threadIdx.x & 63;
    const int wid   = threadIdx.x >> 6;
    const int chunk = blockIdx.x * 4 + wid;
    if (chunk >= NCH) return;                  // wave-uniform exit, no barriers in kernel

    const int c0 = chunk * CW;
    const int r0 = blockIdx.y * RPW;
    const int b  = blockIdx.z;

    const float* __restrict__ xb = x + (long)b * (HH * WW);
    float* __restrict__ outb     = out + (long)b * 9 * PL;

    // masks: uniform indices -> scalar loads / SGPRs
    float m[NOR][9];
#pragma unroll
    for (int o = 0; o < NOR; ++o)
#pragma unroll
        for (int k = 0; k < 9; ++k)
            m[o][k] = masks[o * 9 + k];

    const int j  = c0 + lane;                  // this lane's one-hot column (<= 1023)
    const int ja = j     < 1023 ? j     : 1023; // clamped taps: garbage only feeds
    const int jb = j + 1 < 1023 ? j + 1 : 1023; // halo cols >= 1018 (never stored)
    const int jc = j + 2 < 1023 ? j + 2 : 1023;

    // rolling x-tap window: rows h, h+1 live; row h+2 loaded per iteration
    float t00, t01, t02, t10, t11, t12;
    {
        const float* r = xb + r0 * WW;         // r0 <= 1008: rows r0, r0+1 in range
        t00 = r[ja]; t01 = r[jb]; t02 = r[jc];
        r += WW;
        t10 = r[ja]; t11 = r[jb]; t12 = r[jc];
    }

    unsigned long long rs[5];                  // rolling horizontal 5-sums (registers)

    for (int g = 0; g < 4; ++g) {
#pragma unroll
        for (int p = 0; p < 5; ++p) {
            const int it = g * 5 + p;          // hs-row index offset: 0..19

            // load x row r0+it+2 (clamp: only stripe 63's guarded tail iterations)
            int hr = r0 + it + 2; if (hr > HH - 1) hr = HH - 1;
            const float* rp = xb + hr * WW;
            const float n0 = rp[ja], n1 = rp[jb], n2 = rp[jc];

            // conv -> argmax -> threshold (FMA chain order identical to R2/R3
            // -> bit-identical results, absmax stays 0)
            const float xv[9] = { t00, t01, t02, t10, t11, t12, n0, n1, n2 };
            float best = 0.0f; int bi = 0;
#pragma unroll
            for (int o = 0; o < NOR; ++o) {
                float acc = xv[0] * m[o][0];
#pragma unroll
                for (int k = 1; k < 9; ++k)
                    acc = fmaf(xv[k], m[o][k], acc);
                if (o == 0)          { best = acc; bi = 0; }
                else if (acc > best) { best = acc; bi = o; }
            }
            if (best < 0.9f) bi = NOR;

            // horizontal 5-window: neighbor bins via shuffle (wraps past lane 63
            // -> garbage only in halo lanes 60-63, never stored)
            const int b1 = __shfl(bi, lane + 1);
            const int b2 = __shfl(bi, lane + 2);
            const int b3 = __shfl(bi, lane + 3);
            const int b4 = __shfl(bi, lane + 4);
            rs[p] = (1ull << (7 * bi)) + (1ull << (7 * b1)) + (1ull << (7 * b2))
                  + (1ull << (7 * b3)) + (1ull << (7 * b4));

            // vertical 5-window + emit one output row
            if (it >= 4) {
                const int ro = r0 + it - 4;
                if (ro < H2 && lane < CW && j < W2) {
                    const unsigned long long s = rs[0] + rs[1] + rs[2] + rs[3] + rs[4];
                    const unsigned off0 = (unsigned)ro * W2 + (unsigned)j;
#pragma unroll
                    for (int k = 0; k < 9; ++k) {
                        const float cv =
                            (float)((unsigned)(s >> (7 * k)) & 0x7Fu) * (1.0f / 25.0f);
                        outb[off0 + (unsigned)(k * PL)] = cv;
                    }
                }
            }

            // roll x-tap window
            t00 = t10; t01 = t11; t02 = t12;
            t10 = n0;  t11 = n1;  t12 = n2;
        }
    }
}

extern "C" void kernel_launch(void* const* d_in, const int* in_sizes, int n_in,
                              void* d_out, int out_size, void* d_ws, size_t ws_size,
                              hipStream_t stream)
{
    const float* x     = (const float*)d_in[0];
    const float* masks = (const float*)d_in[1];
    float* out         = (float*)d_out;

    dim3 grid((NCH + 3) / 4,            // 5  (4 waves/block -> 20 chunk slots, 17 used)
              (H2 + RPW - 1) / RPW,     // 64 row stripes
              16);                      // batch
    ehd_wave<<<grid, 256, 0, stream>>>(x, masks, out);
}

// Round 6
// 701.140 us; speedup vs baseline: 1.0602x; 1.0602x over previous
//
#include <hip/hip_runtime.h>

// EHD layer: 3x3 x 8-orientation conv -> argmax+threshold -> 9-bin one-hot
// -> 5x5 box count / 25.
// R5: R3's full-width row blocks (seamless contiguous plane-row writes, the
// proven lever) + 4 ADJACENT cols/thread (float4 stores, float4 tap loads),
// register vertical 5-window (LDS 48->16.5 KB, 4 blocks/CU), 1 barrier/row.

#define NOR 8
#define HH  1024
#define WW  1024
#define H2  1018
#define W2  1018
#define RPB 16            // output rows per block
#define PL  (H2 * W2)     // output plane elements

__global__ __launch_bounds__(256, 4)
void ehd_r5(const float* __restrict__ x,
            const float* __restrict__ masks,
            float* __restrict__ out)
{
    __shared__ __align__(16) unsigned long long ohrow[2][1032]; // 16.5 KB, dbuf + halo pad

    const int t  = threadIdx.x;
    const int j0 = t * 4;                       // this thread's 4 adjacent cols
    const int r0 = blockIdx.x * RPB;
    const int b  = blockIdx.y;

    const float* __restrict__ xb = x + (long)b * (HH * WW);
    float* __restrict__ outb     = out + (long)b * 9 * (long)PL;

    // masks: uniform -> scalar regs
    float m[NOR][9];
#pragma unroll
    for (int o = 0; o < NOR; ++o)
#pragma unroll
        for (int k = 0; k < 9; ++k)
            m[o][k] = masks[o * 9 + k];

    // tail-pair column (t=255 would read x[1024..1025]: clamp; values unused)
    const int jt = (j0 + 4 <= WW - 2) ? (j0 + 4) : (WW - 2);

    float w0[6], w1[6], nc[6], nn[6];
    auto loadrow = [&](int r, float* d) {
        const float* p = xb + r * WW;
        const float4 a = *(const float4*)(p + j0);   // 16B-aligned
        const float2 c = *(const float2*)(p + jt);   // 8B-aligned
        d[0] = a.x; d[1] = a.y; d[2] = a.z; d[3] = a.w; d[4] = c.x; d[5] = c.y;
    };
    loadrow(r0,     w0);
    loadrow(r0 + 1, w1);
    loadrow(r0 + 2, nc);   // r0+2 <= 1010, in range

    unsigned long long rs[5][4];                 // rolling horizontal 5-sums

    for (int g = 0; g < 4; ++g) {
#pragma unroll
        for (int p5 = 0; p5 < 5; ++p5) {
            const int it = g * 5 + p5;           // 0..19

            // ---- conv -> argmax -> threshold -> packed one-hot, 4 cols
            unsigned long long pk[4];
#pragma unroll
            for (int p = 0; p < 4; ++p) {
                const float xv[9] = { w0[p], w0[p+1], w0[p+2],
                                      w1[p], w1[p+1], w1[p+2],
                                      nc[p], nc[p+1], nc[p+2] };
                float best = 0.0f; int bi = 0;
#pragma unroll
                for (int o = 0; o < NOR; ++o) {
                    float acc = xv[0] * m[o][0];
#pragma unroll
                    for (int k = 1; k < 9; ++k)
                        acc = fmaf(xv[k], m[o][k], acc);  // same chain order -> bit-identical
                    if (o == 0)          { best = acc; bi = 0; }
                    else if (acc > best) { best = acc; bi = o; }
                }
                if (best < 0.9f) bi = NOR;
                pk[p] = 1ull << (7 * bi);
            }
            const int sl = it & 1;
            { ulonglong2 v; v.x = pk[0]; v.y = pk[1]; *(ulonglong2*)&ohrow[sl][j0]     = v; }
            { ulonglong2 v; v.x = pk[2]; v.y = pk[3]; *(ulonglong2*)&ohrow[sl][j0 + 2] = v; }
            __syncthreads();

            // ---- prefetch next bottom x row (latency covered by hsum+stores)
            int nr = r0 + it + 3; if (nr > HH - 1) nr = HH - 1;
            loadrow(nr, nn);

            // ---- horizontal 5-sums: own pk + 4-col halo from thread t+1
            const ulonglong2 q2 = *(const ulonglong2*)&ohrow[sl][j0 + 4];
            const ulonglong2 q3 = *(const ulonglong2*)&ohrow[sl][j0 + 6];
            const unsigned long long h0 = pk[0] + pk[1] + pk[2] + pk[3] + q2.x;
            const unsigned long long h1 = h0 + q2.y - pk[0];   // packed sub: no underflow
            const unsigned long long h2 = h1 + q3.x - pk[1];
            const unsigned long long h3 = h2 + q3.y - pk[2];
            rs[p5][0] = h0; rs[p5][1] = h1; rs[p5][2] = h2; rs[p5][3] = h3;

            // ---- vertical 5-sum + emit one output row (float4 per plane)
            if (it >= 4) {
                const int ro = r0 + it - 4;
                if (ro < H2) {
                    const unsigned long long s0 = rs[0][0]+rs[1][0]+rs[2][0]+rs[3][0]+rs[4][0];
                    const unsigned long long s1 = rs[0][1]+rs[1][1]+rs[2][1]+rs[3][1]+rs[4][1];
                    const unsigned long long s2 = rs[0][2]+rs[1][2]+rs[2][2]+rs[3][2]+rs[4][2];
                    const unsigned long long s3 = rs[0][3]+rs[1][3]+rs[2][3]+rs[3][3]+rs[4][3];
                    float* orow = outb + (unsigned)ro * W2 + j0;
                    if (t < 254) {
#pragma unroll
                        for (int k = 0; k < 9; ++k) {
                            float4 f;
                            f.x = (float)((unsigned)(s0 >> (7*k)) & 0x7Fu) * (1.0f/25.0f);
                            f.y = (float)((unsigned)(s1 >> (7*k)) & 0x7Fu) * (1.0f/25.0f);
                            f.z = (float)((unsigned)(s2 >> (7*k)) & 0x7Fu) * (1.0f/25.0f);
                            f.w = (float)((unsigned)(s3 >> (7*k)) & 0x7Fu) * (1.0f/25.0f);
                            *(float4*)(orow + (long)k * PL) = f;  // dwordx4: dword-align OK
                        }
                    } else if (t == 254) {                        // cols 1016,1017 only
#pragma unroll
                        for (int k = 0; k < 9; ++k) {
                            float2 f;
                            f.x = (float)((unsigned)(s0 >> (7*k)) & 0x7Fu) * (1.0f/25.0f);
                            f.y = (float)((unsigned)(s1 >> (7*k)) & 0x7Fu) * (1.0f/25.0f);
                            *(float2*)(orow + (long)k * PL) = f;
                        }
                    }                                             // t==255: halo, no store
                }
            }

            // ---- roll tap window
#pragma unroll
            for (int d = 0; d < 6; ++d) { w0[d] = w1[d]; w1[d] = nc[d]; nc[d] = nn[d]; }
        }
    }
}

extern "C" void kernel_launch(void* const* d_in, const int* in_sizes, int n_in,
                              void* d_out, int out_size, void* d_ws, size_t ws_size,
                              hipStream_t stream)
{
    const float* x     = (const float*)d_in[0];
    const float* masks = (const float*)d_in[1];
    float* out         = (float*)d_out;

    dim3 grid((H2 + RPB - 1) / RPB,   // 64 row stripes
              16);                    // batch
    ehd_r5<<<grid, 256, 0, stream>>>(x, masks, out);
}